// Round 8
// baseline (104.072 us; speedup 1.0000x reference)
//
#include <hip/hip_runtime.h>
#include <hip/hip_bf16.h>
#include <math.h>

// Problem constants (from reference setup_inputs):
//   support [25, 2560] fp32, query [4096, 2560] fp32, n_way=5, k_shot=5
//   out [4096, 5] fp32 = -dist.reshape(4096,5,5).sum(-1)
//   dist[q][s] = || support[s] - query[q] + 1e-6 ||_2
// Strategy: dist^2 = ||s+eps||^2 - 2*(s.q + eps*sum(q)) + ||q||^2
//   -> 1 FMA per (q,s,d) element.
//
// R7 post-mortem: per-iter barrier + vmcnt(0) drain ate the async gain
// (m97-plateau). R3/R6/R7 all plateau ~22-30 us: every block re-reads all
// 256 KB of support through L1/L2 registers (266 MB chip-wide over QR=4).
// R8 restructure: support is the REUSED operand -> stage it in LDS, amortize
// over QB=8 rows/block. 512 blocks x 256 thr; per 256-float chunk stage
// 25 sup + 8 q rows (33 KB) via global_load_lds (double-buffered), each wave
// dots its 2 private rows against all 25 sups from LDS. Sup global traffic
// 266 -> 131 MB (L2->LDS); q streamed once (42 MB HBM). LDS 69 KB -> 2
// blocks/CU, 8 waves/CU.

#define EPS 1e-6f
#define D 2560
#define NSUP 25
#define NQ 4096
#define NWAY 5
#define KSHOT 5

#define QB 8           // query rows per block (2 per wave)
#define BT 256         // 4 waves
#define KITER 10       // D / CH
#define CH 256         // floats per chunk
#define SRN 33         // stage rows per chunk: 25 sup + 8 q (1 KB each)
#define NACC 54        // 50 dots + 2 sumq + 2 normq
#define RSTR 55        // reduction stride (odd -> conflict-free column reads)

// async global->LDS: lane i's 16 B land at lds_base + 16*i (wave-uniform base)
__device__ __forceinline__ void async_q16(const float* gp, float* lp) {
    __builtin_amdgcn_global_load_lds(
        (const __attribute__((address_space(1))) void*)gp,
        (__attribute__((address_space(3))) void*)lp,
        16, 0, 0);
}

__device__ __forceinline__ float dot4(float4 a, float4 b) {
    return a.x * b.x + a.y * b.y + a.z * b.z + a.w * b.w;
}

// ---- prep: ns[s] = || support[s] + eps ||^2  (25 floats into workspace) ----
__global__ void prep_kernel(const float* __restrict__ sup, float* __restrict__ ns) {
    const int s = blockIdx.x;
    const int t = threadIdx.x;  // 256 threads
    float p = 0.f;
    #pragma unroll
    for (int k = 0; k < 10; ++k) {
        float v = sup[s * D + t + 256 * k] + EPS;
        p += v * v;
    }
    __shared__ float red[256];
    red[t] = p;
    __syncthreads();
    for (int off = 128; off > 0; off >>= 1) {
        if (t < off) red[t] += red[t + off];
        __syncthreads();
    }
    if (t == 0) ns[s] = red[0];
}

// stage rows [0..24]=sup, [25..32]=q rows row0..row0+7, chunk j, into dst
__device__ __forceinline__ void stage_chunk(const float* __restrict__ sup,
                                            const float* __restrict__ q,
                                            int row0, int wave, int lane, int j,
                                            float* dst) {
    for (int sr = wave; sr < SRN; sr += 4) {   // sr is wave-uniform
        const float* src = (sr < NSUP)
            ? &sup[sr * D + CH * j + 4 * lane]
            : &q[(row0 + sr - NSUP) * D + CH * j + 4 * lane];
        async_q16(src, dst + sr * CH);
    }
}

// ---- main: 8 q rows per block; support tile shared via LDS ----
__global__ __launch_bounds__(BT, 2)   // NOT (BT,4): 64-VGPR budget would spill acc
void pairwise_kernel(const float* __restrict__ q, const float* __restrict__ sup,
                     const float* __restrict__ ns, float* __restrict__ out) {
    const int t = threadIdx.x;
    const int lane = t & 63;
    const int wave = t >> 6;          // 0..3; wave owns q rows row0+2w, row0+2w+1
    const int row0 = blockIdx.x * QB;

    // smem: during k-loop = double-buffered stage tile [2][33][256] (67.6 KB);
    // after the final barrier it is reused as 4 per-wave 64x55 reduction pads
    // (56.3 KB alias).
    __shared__ float smem[2 * SRN * CH];
    __shared__ float wsum[4 * NACC];   // per-wave reduced values
    __shared__ float dists[QB * NSUP];

    // prologue: stage chunk 0 into buffer 0 (acc init overlaps the latency)
    stage_chunk(sup, q, row0, wave, lane, 0, &smem[0]);

    // acc[r*25+s] = partial dot(sup[s], q[row0+2*wave+r]) over this lane's slices
    // acc[50+r] = partial sum(q row); acc[52+r] = partial ||q row||^2
    // ALL acc indices compile-time (SROA -> registers; R2-R5 lesson).
    float acc[NACC];
    #pragma unroll
    for (int i = 0; i < NACC; ++i) acc[i] = 0.f;

    __syncthreads();   // chunk 0 landed

    #pragma unroll 1
    for (int j = 0; j < KITER; ++j) {
        const int cur = j & 1;
        const float* bufc = &smem[cur * SRN * CH];

        // prefetch next chunk into the other buffer FIRST (latency covered by
        // this iteration's compute; landed by the end-of-iter barrier drain)
        if (j < KITER - 1)
            stage_chunk(sup, q, row0, wave, lane, j + 1, &smem[(cur ^ 1) * SRN * CH]);

        // this wave's 2 query rows (private), from LDS
        const float4 qv0 = *reinterpret_cast<const float4*>(
                               &bufc[(NSUP + 2 * wave + 0) * CH + 4 * lane]);
        const float4 qv1 = *reinterpret_cast<const float4*>(
                               &bufc[(NSUP + 2 * wave + 1) * CH + 4 * lane]);
        acc[50] += (qv0.x + qv0.y) + (qv0.z + qv0.w);
        acc[51] += (qv1.x + qv1.y) + (qv1.z + qv1.w);
        acc[52] += dot4(qv0, qv0);
        acc[53] += dot4(qv1, qv1);

        // 25 support rows from LDS, groups of 5 (caps a4 at 20 VGPRs)
        #pragma unroll
        for (int g = 0; g < NSUP; g += 5) {
            float4 a4[5];
            #pragma unroll
            for (int jj = 0; jj < 5; ++jj)
                a4[jj] = *reinterpret_cast<const float4*>(
                             &bufc[(g + jj) * CH + 4 * lane]);
            #pragma unroll
            for (int jj = 0; jj < 5; ++jj) {
                acc[g + jj]        += dot4(a4[jj], qv0);
                acc[25 + g + jj]   += dot4(a4[jj], qv1);
            }
        }

        __syncthreads();   // next buffer staged; cur buffer free for j+2 staging
    }

    // ---- cross-lane reduction: per-wave 64x55 LDS pad (aliases stage tile) ----
    float* wr = &smem[wave * 64 * RSTR];
    #pragma unroll
    for (int v = 0; v < NACC; ++v) wr[lane * RSTR + v] = acc[v];
    __syncthreads();
    if (lane < NACC) {
        float s0 = 0.f, s1 = 0.f, s2 = 0.f, s3 = 0.f;
        for (int i = 0; i < 64; i += 4) {
            s0 += wr[(i + 0) * RSTR + lane];
            s1 += wr[(i + 1) * RSTR + lane];
            s2 += wr[(i + 2) * RSTR + lane];
            s3 += wr[(i + 3) * RSTR + lane];
        }
        wsum[wave * NACC + lane] = (s0 + s1) + (s2 + s3);
    }
    __syncthreads();

    // ---- epilogue: dist = sqrt(ns + ||q||^2 - 2*(dot + eps*sumq)) ----
    if (t < QB * NSUP) {               // 200 threads: r in 0..7, s in 0..24
        const int r = t / NSUP, s = t % NSUP;
        const int w = r >> 1, lr = r & 1;
        const float dot  = wsum[w * NACC + lr * 25 + s];
        const float sumq = wsum[w * NACC + 50 + lr];
        const float nq   = wsum[w * NACC + 52 + lr];
        const float d2 = ns[s] + nq - 2.f * (dot + EPS * sumq);
        dists[t] = sqrtf(fmaxf(d2, 0.f));
    }
    __syncthreads();
    if (t < QB * NWAY) {               // 40 threads
        const int r = t / NWAY, w = t % NWAY;
        float sc = 0.f;
        #pragma unroll
        for (int jj = 0; jj < KSHOT; ++jj) sc += dists[r * NSUP + w * KSHOT + jj];
        out[(row0 + r) * NWAY + w] = -sc;
    }
}

extern "C" void kernel_launch(void* const* d_in, const int* in_sizes, int n_in,
                              void* d_out, int out_size, void* d_ws, size_t ws_size,
                              hipStream_t stream) {
    const float* support = (const float*)d_in[0];
    const float* query   = (const float*)d_in[1];
    // d_in[2]=n_way(5), d_in[3]=k_shot(5): hardcoded per setup_inputs.
    float* out = (float*)d_out;
    float* ns  = (float*)d_ws;   // 25 floats of scratch

    prep_kernel<<<NSUP, 256, 0, stream>>>(support, ns);
    pairwise_kernel<<<NQ / QB, BT, 0, stream>>>(query, support, ns, out);
}